// Round 14
// baseline (117.585 us; speedup 1.0000x reference)
//
#include <hip/hip_runtime.h>
#include <hip/hip_bf16.h>
#include <cstdint>

using short8 = __attribute__((ext_vector_type(8))) short;
using f32x4  = __attribute__((ext_vector_type(4))) float;

constexpr int CAP = 8192;   // per-bucket segment capacity (mean 4096, std ~64)

// bf16 helpers (finite values only)
__device__ __forceinline__ unsigned f2bf_bits(float f) {
    unsigned u = __float_as_uint(f);
    return (u + 0x7fffu + ((u >> 16) & 1u)) >> 16;   // RNE
}
__device__ __forceinline__ float bf_lo(unsigned u) { return __uint_as_float(u << 16); }
__device__ __forceinline__ float bf_hi(unsigned u) { return __uint_as_float(u & 0xffff0000u); }

// ---------------- W pre-pack (all 3 layers) + zero bucket cursors ----------------

__device__ __forceinline__ void prepack_one(const float* __restrict__ W,
                                            short* __restrict__ Wh, short* __restrict__ Wl,
                                            int DOUT, int idx) {
    int lane = idx & 63, tile = idx >> 6;
    int NT = DOUT / 16;
    int kk = tile / NT, ct = tile - kk * NT;
    int g = lane >> 4, cl = lane & 15;
    int c = ct * 16 + cl;
    short8 h8, l8;
#pragma unroll
    for (int j = 0; j < 8; ++j) {
        float w = W[(size_t)(kk * 32 + g * 8 + j) * DOUT + c];
        unsigned hb = f2bf_bits(w);
        unsigned lb = f2bf_bits(w - bf_lo(hb));
        h8[j] = (short)hb; l8[j] = (short)lb;
    }
    *reinterpret_cast<short8*>(&Wh[(size_t)idx * 8]) = h8;
    *reinterpret_cast<short8*>(&Wl[(size_t)idx * 8]) = l8;
}

__global__ __launch_bounds__(256) void prepack_all_kernel(const float* __restrict__ W1,
                                                          const float* __restrict__ W2,
                                                          const float* __restrict__ W3,
                                                          short* __restrict__ w1h, short* __restrict__ w1l,
                                                          short* __restrict__ w2h, short* __restrict__ w2l,
                                                          short* __restrict__ w3h, short* __restrict__ w3l,
                                                          int* __restrict__ bkt_cursor) {
    int idx = blockIdx.x * 256 + threadIdx.x;
    if (idx < 2048)      prepack_one(W1, w1h, w1l, 128, idx);
    else if (idx < 3072) prepack_one(W2, w2h, w2l, 64,  idx - 2048);
    else if (idx < 3328) prepack_one(W3, w3h, w3l, 32,  idx - 3072);
    else if (idx < 3584) bkt_cursor[idx - 3328] = 0;
}

// ---------------- merged: edge binning (blocks < NBE)  ∥  layer-1 GEMM (blocks >= NBE) ------------

struct BinSh {
    int qcnt[256];
    int qofs[256];
    int gbase[256];
    uint2 staging[4096];
};
struct GemmSh {
    unsigned Xh[64 * 64];
    unsigned Xl[64 * 64];
};
union SharedU { BinSh b; GemmSh g; };

__global__ __launch_bounds__(512) void bin_gemm1_kernel(const int* __restrict__ src,
                                                        const int* __restrict__ dst, int E,
                                                        int* __restrict__ bkt_cursor,
                                                        unsigned* __restrict__ bin,
                                                        const float* __restrict__ X,
                                                        const short8* __restrict__ Wp_hi,
                                                        const short8* __restrict__ Wp_lo,
                                                        unsigned* __restrict__ G,
                                                        int n, int NBE) {
    __shared__ SharedU sh;
    const int t = threadIdx.x;

    if ((int)blockIdx.x < NBE) {
        const int e0 = (int)blockIdx.x * 4096;
        if (t < 256) sh.b.qcnt[t] = 0;
        __syncthreads();
        int sa[8], da[8], slot[8];
#pragma unroll
        for (int k = 0; k < 8; ++k) {
            int e = e0 + k * 512 + t;
            sa[k] = -1; da[k] = 0; slot[k] = 0;
            if (e < E) {
                int ss = src[e], dd = dst[e];
                if (ss >= 0 && ss < n && dd >= 0 && dd < n) {
                    sa[k] = ss; da[k] = dd;
                    slot[k] = atomicAdd(&sh.b.qcnt[dd >> 8], 1);
                }
            }
        }
        __syncthreads();
        if (t < 256) sh.b.qofs[t] = sh.b.qcnt[t];
        __syncthreads();
        for (int off = 1; off < 256; off <<= 1) {
            int val = 0;
            if (t < 256 && t >= off) val = sh.b.qofs[t - off];
            __syncthreads();
            if (t < 256) sh.b.qofs[t] += val;
            __syncthreads();
        }
        if (t < 256) {
            int myc = sh.b.qcnt[t];
            if (myc > 0) sh.b.gbase[t] = atomicAdd(&bkt_cursor[t], myc);
            sh.b.qofs[t] -= myc;
        }
        __syncthreads();
#pragma unroll
        for (int k = 0; k < 8; ++k) {
            if (sa[k] >= 0)
                sh.b.staging[sh.b.qofs[da[k] >> 8] + slot[k]] =
                    make_uint2((unsigned)sa[k], (unsigned)da[k]);
        }
        __syncthreads();
        const int tot = sh.b.qofs[255] + sh.b.qcnt[255];
        for (int i = t; i < tot; i += 512) {
            uint2 en = sh.b.staging[i];
            int b = (int)(en.y >> 8);
            int pos = sh.b.gbase[b] + (i - sh.b.qofs[b]);
            if (pos < CAP)
                bin[(size_t)b * CAP + pos] = ((en.y & 255u) << 24) | en.x;
        }
        return;
    }

    // ---- layer-1 GEMM body: DIN=128, DOUT=128, UNSCALED output ----
    constexpr int NT = 8, NTW = 4, NK = 4, WPR = 64;
    const int row0 = ((int)blockIdx.x - NBE) * 64;

    for (int i = t * 4; i < 64 * 128; i += 2048) {
        int r = i / 128, c = i % 128;
        float4 v = make_float4(0.f, 0.f, 0.f, 0.f);
        if (row0 + r < n) v = *reinterpret_cast<const float4*>(&X[(size_t)(row0 + r) * 128 + c]);
        unsigned h0 = f2bf_bits(v.x), h1 = f2bf_bits(v.y), h2 = f2bf_bits(v.z), h3 = f2bf_bits(v.w);
        unsigned l0 = f2bf_bits(v.x - bf_lo(h0)), l1 = f2bf_bits(v.y - bf_lo(h1));
        unsigned l2 = f2bf_bits(v.z - bf_lo(h2)), l3 = f2bf_bits(v.w - bf_lo(h3));
        int w = (r * WPR + c / 2) ^ ((r & 7) << 2);
        *reinterpret_cast<uint2*>(&sh.g.Xh[w]) = make_uint2(h0 | (h1 << 16), h2 | (h3 << 16));
        *reinterpret_cast<uint2*>(&sh.g.Xl[w]) = make_uint2(l0 | (l1 << 16), l2 | (l3 << 16));
    }
    __syncthreads();

    const int lane = t & 63, wid = t >> 6;
    const int strip = wid >> 1, half = wid & 1;
    const int g = lane >> 4, cl = lane & 15;
    const int lrow = strip * 16 + cl;
    f32x4 acc[NTW];
#pragma unroll
    for (int i = 0; i < NTW; ++i) acc[i] = (f32x4){0.f, 0.f, 0.f, 0.f};

#pragma unroll
    for (int kk = 0; kk < NK; ++kk) {
        int wb = (lrow * WPR + kk * 16 + g * 4) ^ ((lrow & 7) << 2);
        short8 xh = *reinterpret_cast<const short8*>(&sh.g.Xh[wb]);
        short8 xl = *reinterpret_cast<const short8*>(&sh.g.Xl[wb]);
#pragma unroll
        for (int i = 0; i < NTW; ++i) {
            int ct = half * NTW + i;
            short8 wh = Wp_hi[(kk * NT + ct) * 64 + lane];
            short8 wl = Wp_lo[(kk * NT + ct) * 64 + lane];
            acc[i] = __builtin_amdgcn_mfma_f32_16x16x32_bf16(wh, xh, acc[i], 0, 0, 0);
            acc[i] = __builtin_amdgcn_mfma_f32_16x16x32_bf16(wh, xl, acc[i], 0, 0, 0);
            acc[i] = __builtin_amdgcn_mfma_f32_16x16x32_bf16(wl, xh, acc[i], 0, 0, 0);
        }
    }

    const int r = row0 + lrow;
    if (r < n) {
#pragma unroll
        for (int i = 0; i < NTW; ++i) {
            int c0 = (half * NTW + i) * 16 + g * 4;
            unsigned p0 = f2bf_bits(acc[i][0]) | (f2bf_bits(acc[i][1]) << 16);
            unsigned p1 = f2bf_bits(acc[i][2]) | (f2bf_bits(acc[i][3]) << 16);
            *reinterpret_cast<uint2*>(&G[(size_t)r * 64 + c0 / 2]) = make_uint2(p0, p1);
        }
    }
}

// per-bucket: offsets + dinv + csr fill + g1 pre-scale
__global__ __launch_bounds__(256) void bucket_offsets_fill_kernel(const unsigned* __restrict__ bin,
                                                                  const int* __restrict__ bkt_cursor,
                                                                  int2* __restrict__ off2,
                                                                  float* __restrict__ dinv,
                                                                  int* __restrict__ csr,
                                                                  unsigned* __restrict__ g1, int n) {
    __shared__ int cnt[256];
    __shared__ int sh[256];
    __shared__ int cur[256];
    __shared__ float sdinv[256];
    const int t = threadIdx.x;
    const int b = blockIdx.x;
    const int S = b * CAP;
    const int count = min(bkt_cursor[b], CAP);
    cnt[t] = 0;
    __syncthreads();
    for (int i = t; i < count; i += 256) atomicAdd(&cnt[bin[S + i] >> 24], 1);
    __syncthreads();
    const int c = cnt[t];
    sh[t] = c;
    __syncthreads();
    for (int off = 1; off < 256; off <<= 1) {
        int val = (t >= off) ? sh[t - off] : 0;
        __syncthreads();
        sh[t] += val;
        __syncthreads();
    }
    const int start = S + sh[t] - c;
    cur[t] = start;
    const float dv = rsqrtf((float)(c + 1));
    sdinv[t] = dv;
    const int node0 = b * 256;
    const int node = node0 + t;
    if (node < n) {
        off2[node] = make_int2(start, start + c);
        dinv[node] = dv;
    }
    __syncthreads();
    for (int i = t; i < count; i += 256) {
        unsigned p = bin[S + i];
        int pos = atomicAdd(&cur[p >> 24], 1);
        csr[pos] = (int)(p & 0xFFFFFFu);
    }
    const int rows = min(256, n - node0);
    uint4* g4 = reinterpret_cast<uint4*>(g1 + (size_t)node0 * 64);
    for (int i = t; i < rows * 16; i += 256) {
        const float s = sdinv[i >> 4];
        uint4 v = g4[i];
        unsigned r0 = f2bf_bits(s * bf_lo(v.x)) | (f2bf_bits(s * bf_hi(v.x)) << 16);
        unsigned r1 = f2bf_bits(s * bf_lo(v.y)) | (f2bf_bits(s * bf_hi(v.y)) << 16);
        unsigned r2 = f2bf_bits(s * bf_lo(v.z)) | (f2bf_bits(s * bf_hi(v.z)) << 16);
        unsigned r3 = f2bf_bits(s * bf_lo(v.w)) | (f2bf_bits(s * bf_hi(v.w)) << 16);
        g4[i] = make_uint4(r0, r1, r2, r3);
    }
}

// ------- FUSED: h[v] = relu(dinv[v]*(g[v]+Σ g[u]) + b)  ->  Gout = bf16(diag(dinv)·(h @ W)) -------
// csr segment LDS-staged (contiguous per 64-node tile); launch_bounds(512,4) -> VGPR headroom
// so the unroll-8 row loads actually stay in flight.

template<int DIN, int DOUT>
__global__ __launch_bounds__(512, 4) void fused_agg_gemm_kernel(const unsigned* __restrict__ Gin,
                                                                const int2* __restrict__ off2,
                                                                const int* __restrict__ csr,
                                                                const float* __restrict__ dinv,
                                                                const float* __restrict__ bias,
                                                                const short8* __restrict__ Wp_hi,
                                                                const short8* __restrict__ Wp_lo,
                                                                unsigned* __restrict__ Gout, int n) {
    constexpr int NT    = DOUT / 16;
    constexpr int NTW   = NT / 2;
    constexpr int NK    = DIN / 32;
    constexpr int WPR   = DIN / 2;
    constexpr int W4    = DIN / 8;
    constexpr int LPN   = W4;
    constexpr int SLOTS = 512 / LPN;
    constexpr int ROUNDS = 64 / SLOTS;
    constexpr int STG   = 2048;          // staged csr entries (mean ~1090, >25 sigma margin)
    __shared__ unsigned Xh[64 * WPR];
    __shared__ unsigned Xl[64 * WPR];
    __shared__ int scsr[STG];
    const int t = threadIdx.x;
    const int node0 = blockIdx.x * 64;
    const int slot = t / LPN, cw = t % LPN;
    const uint4* gB = reinterpret_cast<const uint4*>(Gin) + cw;
    const int col = cw * 8;
    const float4 bs0 = *reinterpret_cast<const float4*>(&bias[col]);
    const float4 bs1 = *reinterpret_cast<const float4*>(&bias[col + 4]);

    // stage this tile's csr segment (contiguous: 64 consecutive nodes, same bucket)
    const int blkS = off2[node0].x;
    const int blkE = off2[min(node0 + 63, n - 1)].y;
    const int stg = min(blkE - blkS, STG);
    for (int i = t; i < stg; i += 512) scsr[i] = csr[blkS + i];
    __syncthreads();

#pragma unroll
    for (int rd = 0; rd < ROUNDS; ++rd) {
        const int r = rd * SLOTS + slot;
        const int v = node0 + r;
        unsigned hw[4] = {0u, 0u, 0u, 0u}, lw[4] = {0u, 0u, 0u, 0u};
        if (v < n) {
            float a[8], b[8];
            uint4 us = gB[(size_t)v * W4];
            a[0] = bf_lo(us.x); a[1] = bf_hi(us.x); a[2] = bf_lo(us.y); a[3] = bf_hi(us.y);
            a[4] = bf_lo(us.z); a[5] = bf_hi(us.z); a[6] = bf_lo(us.w); a[7] = bf_hi(us.w);
#pragma unroll
            for (int q = 0; q < 8; ++q) b[q] = 0.f;
            const int2 se = off2[v];
            int j = se.x;
            for (; j + 8 <= se.y; j += 8) {
                int k = j - blkS;
                int u0, u1, u2, u3, u4, u5, u6, u7;
                if (k + 8 <= stg) {
                    u0 = scsr[k];     u1 = scsr[k + 1]; u2 = scsr[k + 2]; u3 = scsr[k + 3];
                    u4 = scsr[k + 4]; u5 = scsr[k + 5]; u6 = scsr[k + 6]; u7 = scsr[k + 7];
                } else {
                    u0 = csr[j];      u1 = csr[j + 1];  u2 = csr[j + 2];  u3 = csr[j + 3];
                    u4 = csr[j + 4];  u5 = csr[j + 5];  u6 = csr[j + 6];  u7 = csr[j + 7];
                }
                uint4 x0 = gB[(size_t)u0 * W4];
                uint4 x1 = gB[(size_t)u1 * W4];
                uint4 x2 = gB[(size_t)u2 * W4];
                uint4 x3 = gB[(size_t)u3 * W4];
                uint4 x4 = gB[(size_t)u4 * W4];
                uint4 x5 = gB[(size_t)u5 * W4];
                uint4 x6 = gB[(size_t)u6 * W4];
                uint4 x7 = gB[(size_t)u7 * W4];
                a[0] += bf_lo(x0.x); a[1] += bf_hi(x0.x); a[2] += bf_lo(x0.y); a[3] += bf_hi(x0.y);
                a[4] += bf_lo(x0.z); a[5] += bf_hi(x0.z); a[6] += bf_lo(x0.w); a[7] += bf_hi(x0.w);
                b[0] += bf_lo(x1.x); b[1] += bf_hi(x1.x); b[2] += bf_lo(x1.y); b[3] += bf_hi(x1.y);
                b[4] += bf_lo(x1.z); b[5] += bf_hi(x1.z); b[6] += bf_lo(x1.w); b[7] += bf_hi(x1.w);
                a[0] += bf_lo(x2.x); a[1] += bf_hi(x2.x); a[2] += bf_lo(x2.y); a[3] += bf_hi(x2.y);
                a[4] += bf_lo(x2.z); a[5] += bf_hi(x2.z); a[6] += bf_lo(x2.w); a[7] += bf_hi(x2.w);
                b[0] += bf_lo(x3.x); b[1] += bf_hi(x3.x); b[2] += bf_lo(x3.y); b[3] += bf_hi(x3.y);
                b[4] += bf_lo(x3.z); b[5] += bf_hi(x3.z); b[6] += bf_lo(x3.w); b[7] += bf_hi(x3.w);
                a[0] += bf_lo(x4.x); a[1] += bf_hi(x4.x); a[2] += bf_lo(x4.y); a[3] += bf_hi(x4.y);
                a[4] += bf_lo(x4.z); a[5] += bf_hi(x4.z); a[6] += bf_lo(x4.w); a[7] += bf_hi(x4.w);
                b[0] += bf_lo(x5.x); b[1] += bf_hi(x5.x); b[2] += bf_lo(x5.y); b[3] += bf_hi(x5.y);
                b[4] += bf_lo(x5.z); b[5] += bf_hi(x5.z); b[6] += bf_lo(x5.w); b[7] += bf_hi(x5.w);
                a[0] += bf_lo(x6.x); a[1] += bf_hi(x6.x); a[2] += bf_lo(x6.y); a[3] += bf_hi(x6.y);
                a[4] += bf_lo(x6.z); a[5] += bf_hi(x6.z); a[6] += bf_lo(x6.w); a[7] += bf_hi(x6.w);
                b[0] += bf_lo(x7.x); b[1] += bf_hi(x7.x); b[2] += bf_lo(x7.y); b[3] += bf_hi(x7.y);
                b[4] += bf_lo(x7.z); b[5] += bf_hi(x7.z); b[6] += bf_lo(x7.w); b[7] += bf_hi(x7.w);
            }
            for (; j < se.y; ++j) {
                int k = j - blkS;
                int u0 = (k < stg) ? scsr[k] : csr[j];
                uint4 x0 = gB[(size_t)u0 * W4];
                a[0] += bf_lo(x0.x); a[1] += bf_hi(x0.x); a[2] += bf_lo(x0.y); a[3] += bf_hi(x0.y);
                a[4] += bf_lo(x0.z); a[5] += bf_hi(x0.z); a[6] += bf_lo(x0.w); a[7] += bf_hi(x0.w);
            }
            const float dv = dinv[v];
            const float bb[8] = {bs0.x, bs0.y, bs0.z, bs0.w, bs1.x, bs1.y, bs1.z, bs1.w};
#pragma unroll
            for (int q = 0; q < 8; ++q) {
                float o = fmaxf(dv * (a[q] + b[q]) + bb[q], 0.f);   // ReLU
                unsigned hb = f2bf_bits(o);
                unsigned lb = f2bf_bits(o - bf_lo(hb));
                hw[q >> 1] |= (q & 1) ? (hb << 16) : hb;
                lw[q >> 1] |= (q & 1) ? (lb << 16) : lb;
            }
        }
        const int w0 = (r * WPR + cw * 4) ^ ((r & 7) << 2);
        *reinterpret_cast<uint4*>(&Xh[w0]) = make_uint4(hw[0], hw[1], hw[2], hw[3]);
        *reinterpret_cast<uint4*>(&Xl[w0]) = make_uint4(lw[0], lw[1], lw[2], lw[3]);
    }
    __syncthreads();

    // MFMA phase (wave pair per strip, NT split in halves)
    const int lane = t & 63, wid = t >> 6;
    const int strip = wid >> 1, half = wid & 1;
    const int g = lane >> 4, cl = lane & 15;
    const int lrow = strip * 16 + cl;
    f32x4 acc[NTW];
#pragma unroll
    for (int i = 0; i < NTW; ++i) acc[i] = (f32x4){0.f, 0.f, 0.f, 0.f};

#pragma unroll
    for (int kk = 0; kk < NK; ++kk) {
        int wb = (lrow * WPR + kk * 16 + g * 4) ^ ((lrow & 7) << 2);
        short8 xh = *reinterpret_cast<const short8*>(&Xh[wb]);
        short8 xl = *reinterpret_cast<const short8*>(&Xl[wb]);
#pragma unroll
        for (int i = 0; i < NTW; ++i) {
            int ct = half * NTW + i;
            short8 wh = Wp_hi[(kk * NT + ct) * 64 + lane];
            short8 wl = Wp_lo[(kk * NT + ct) * 64 + lane];
            acc[i] = __builtin_amdgcn_mfma_f32_16x16x32_bf16(wh, xh, acc[i], 0, 0, 0);
            acc[i] = __builtin_amdgcn_mfma_f32_16x16x32_bf16(wh, xl, acc[i], 0, 0, 0);
            acc[i] = __builtin_amdgcn_mfma_f32_16x16x32_bf16(wl, xh, acc[i], 0, 0, 0);
        }
    }

    const int r = node0 + lrow;
    if (r < n) {
        const float s = dinv[r];
#pragma unroll
        for (int i = 0; i < NTW; ++i) {
            int c0 = (half * NTW + i) * 16 + g * 4;
            unsigned p0 = f2bf_bits(acc[i][0] * s) | (f2bf_bits(acc[i][1] * s) << 16);
            unsigned p1 = f2bf_bits(acc[i][2] * s) | (f2bf_bits(acc[i][3] * s) << 16);
            *reinterpret_cast<uint2*>(&Gout[(size_t)r * (DOUT / 2) + c0 / 2]) = make_uint2(p0, p1);
        }
    }
}

// -------- Final aggregate (D=32, no relu, fp32 out) -- csr LDS-staged, launch_bounds(256,4) -----

__global__ __launch_bounds__(256, 4) void aggregate_final_kernel(const unsigned* __restrict__ G,
                                                                 const int2* __restrict__ off2,
                                                                 const int* __restrict__ csr,
                                                                 const float* __restrict__ dinv,
                                                                 const float* __restrict__ bias,
                                                                 float* __restrict__ out, int n) {
    constexpr int D = 32, W2u = 8, LPN = 8, STG = 1024;
    __shared__ int scsr[STG];
    const int t = threadIdx.x;
    const int v0 = blockIdx.x * 32;
    const int blkS = off2[v0].x;
    const int blkE = off2[min(v0 + 31, n - 1)].y;
    const int stg = min(blkE - blkS, STG);
    for (int i = t; i < stg; i += 256) scsr[i] = csr[blkS + i];
    __syncthreads();

    const int v = v0 + t / LPN;
    if (v >= n) return;
    const int cw = t % LPN;
    const uint2* gB = reinterpret_cast<const uint2*>(G) + cw;

    float a[4], b[4];
    uint2 us = gB[(size_t)v * W2u];
    a[0] = bf_lo(us.x); a[1] = bf_hi(us.x); a[2] = bf_lo(us.y); a[3] = bf_hi(us.y);
#pragma unroll
    for (int q = 0; q < 4; ++q) b[q] = 0.f;

    const int2 se = off2[v];
    int j = se.x;
    for (; j + 8 <= se.y; j += 8) {
        int k = j - blkS;
        int u0, u1, u2, u3, u4, u5, u6, u7;
        if (k + 8 <= stg) {
            u0 = scsr[k];     u1 = scsr[k + 1]; u2 = scsr[k + 2]; u3 = scsr[k + 3];
            u4 = scsr[k + 4]; u5 = scsr[k + 5]; u6 = scsr[k + 6]; u7 = scsr[k + 7];
        } else {
            u0 = csr[j];      u1 = csr[j + 1];  u2 = csr[j + 2];  u3 = csr[j + 3];
            u4 = csr[j + 4];  u5 = csr[j + 5];  u6 = csr[j + 6];  u7 = csr[j + 7];
        }
        uint2 x0 = gB[(size_t)u0 * W2u];
        uint2 x1 = gB[(size_t)u1 * W2u];
        uint2 x2 = gB[(size_t)u2 * W2u];
        uint2 x3 = gB[(size_t)u3 * W2u];
        uint2 x4 = gB[(size_t)u4 * W2u];
        uint2 x5 = gB[(size_t)u5 * W2u];
        uint2 x6 = gB[(size_t)u6 * W2u];
        uint2 x7 = gB[(size_t)u7 * W2u];
        a[0] += bf_lo(x0.x); a[1] += bf_hi(x0.x); a[2] += bf_lo(x0.y); a[3] += bf_hi(x0.y);
        b[0] += bf_lo(x1.x); b[1] += bf_hi(x1.x); b[2] += bf_lo(x1.y); b[3] += bf_hi(x1.y);
        a[0] += bf_lo(x2.x); a[1] += bf_hi(x2.x); a[2] += bf_lo(x2.y); a[3] += bf_hi(x2.y);
        b[0] += bf_lo(x3.x); b[1] += bf_hi(x3.x); b[2] += bf_lo(x3.y); b[3] += bf_hi(x3.y);
        a[0] += bf_lo(x4.x); a[1] += bf_hi(x4.x); a[2] += bf_lo(x4.y); a[3] += bf_hi(x4.y);
        b[0] += bf_lo(x5.x); b[1] += bf_hi(x5.x); b[2] += bf_lo(x5.y); b[3] += bf_hi(x5.y);
        a[0] += bf_lo(x6.x); a[1] += bf_hi(x6.x); a[2] += bf_lo(x6.y); a[3] += bf_hi(x6.y);
        b[0] += bf_lo(x7.x); b[1] += bf_hi(x7.x); b[2] += bf_lo(x7.y); b[3] += bf_hi(x7.y);
    }
    for (; j < se.y; ++j) {
        int k = j - blkS;
        int u0 = (k < stg) ? scsr[k] : csr[j];
        uint2 x0 = gB[(size_t)u0 * W2u];
        a[0] += bf_lo(x0.x); a[1] += bf_hi(x0.x); a[2] += bf_lo(x0.y); a[3] += bf_hi(x0.y);
    }

    const float dv = dinv[v];
    const int col = cw * 4;
    const float4 bs = *reinterpret_cast<const float4*>(&bias[col]);
    float4 o = make_float4(dv * (a[0] + b[0]) + bs.x, dv * (a[1] + b[1]) + bs.y,
                           dv * (a[2] + b[2]) + bs.z, dv * (a[3] + b[3]) + bs.w);
    *reinterpret_cast<float4*>(&out[(size_t)v * D + col]) = o;
}

// ---------------- launch ----------------

extern "C" void kernel_launch(void* const* d_in, const int* in_sizes, int n_in,
                              void* d_out, int out_size, void* d_ws, size_t ws_size,
                              hipStream_t stream) {
    const int N = 50000, E = 800000;
    const int NB  = (N + 255) / 256;
    const int NBE = (E + 4095) / 4096;
    const int NG  = (N + 63) / 64;
    const float* x  = (const float*)d_in[0];
    const int* ei = (const int*)d_in[1];
    const int* src = ei;
    const int* dst = ei + E;
    const float* W1 = (const float*)d_in[2]; const float* b1 = (const float*)d_in[3];
    const float* W2 = (const float*)d_in[4]; const float* b2 = (const float*)d_in[5];
    const float* W3 = (const float*)d_in[6]; const float* b3 = (const float*)d_in[7];
    float* out = (float*)d_out;

    char* ws = (char*)d_ws;
    size_t off = 0;
    auto alloc = [&](size_t bytes) -> void* {
        void* p = ws + off;
        off = (off + bytes + 255) & ~(size_t)255;
        return p;
    };
    int2*     off2       = (int2*)alloc((size_t)N * 8);
    float*    dinv       = (float*)alloc((size_t)N * 4);
    int*      csr        = (int*)alloc((size_t)NB * CAP * 4);
    unsigned* bin        = (unsigned*)alloc((size_t)NB * CAP * 4);
    unsigned* g1         = (unsigned*)alloc((size_t)N * 64 * 4);
    unsigned* g2         = (unsigned*)alloc((size_t)N * 32 * 4);
    unsigned* g3         = (unsigned*)alloc((size_t)N * 16 * 4);
    int*      bkt_cursor = (int*)alloc((size_t)256 * 4);
    short*    wp1h = (short*)alloc((size_t)128 * 128 * 2);
    short*    wp1l = (short*)alloc((size_t)128 * 128 * 2);
    short*    wp2h = (short*)alloc((size_t)128 * 64 * 2);
    short*    wp2l = (short*)alloc((size_t)128 * 64 * 2);
    short*    wp3h = (short*)alloc((size_t)64 * 32 * 2);
    short*    wp3l = (short*)alloc((size_t)64 * 32 * 2);
    (void)ws_size; (void)n_in; (void)in_sizes; (void)out_size;

    prepack_all_kernel<<<14, 256, 0, stream>>>(W1, W2, W3, wp1h, wp1l, wp2h, wp2l, wp3h, wp3l,
                                               bkt_cursor);
    bin_gemm1_kernel<<<NBE + NG, 512, 0, stream>>>(src, dst, E, bkt_cursor, bin,
                                                   x, (const short8*)wp1h, (const short8*)wp1l,
                                                   g1, N, NBE);
    bucket_offsets_fill_kernel<<<NB, 256, 0, stream>>>(bin, bkt_cursor, off2, dinv, csr, g1, N);
    fused_agg_gemm_kernel<128, 64><<<NG, 512, 0, stream>>>(g1, off2, csr, dinv, b1,
                                                           (const short8*)wp2h,
                                                           (const short8*)wp2l, g2, N);
    fused_agg_gemm_kernel<64, 32><<<NG, 512, 0, stream>>>(g2, off2, csr, dinv, b2,
                                                          (const short8*)wp3h,
                                                          (const short8*)wp3l, g3, N);
    aggregate_final_kernel<<<(N * 8 + 255) / 256, 256, 0, stream>>>(g3, off2, csr, dinv, b3, out, N);
}

// Round 15
// 116.897 us; speedup vs baseline: 1.0059x; 1.0059x over previous
//
#include <hip/hip_runtime.h>
#include <hip/hip_bf16.h>
#include <cstdint>

using short8 = __attribute__((ext_vector_type(8))) short;
using f32x4  = __attribute__((ext_vector_type(4))) float;

constexpr int CAP = 8192;   // per-bucket segment capacity (mean 4096, std ~64)

// bf16 helpers (finite values only)
__device__ __forceinline__ unsigned f2bf_bits(float f) {
    unsigned u = __float_as_uint(f);
    return (u + 0x7fffu + ((u >> 16) & 1u)) >> 16;   // RNE
}
__device__ __forceinline__ float bf_lo(unsigned u) { return __uint_as_float(u << 16); }
__device__ __forceinline__ float bf_hi(unsigned u) { return __uint_as_float(u & 0xffff0000u); }

// ---------------- W pre-pack (all 3 layers) + zero bucket cursors ----------------

__device__ __forceinline__ void prepack_one(const float* __restrict__ W,
                                            short* __restrict__ Wh, short* __restrict__ Wl,
                                            int DOUT, int idx) {
    int lane = idx & 63, tile = idx >> 6;
    int NT = DOUT / 16;
    int kk = tile / NT, ct = tile - kk * NT;
    int g = lane >> 4, cl = lane & 15;
    int c = ct * 16 + cl;
    short8 h8, l8;
#pragma unroll
    for (int j = 0; j < 8; ++j) {
        float w = W[(size_t)(kk * 32 + g * 8 + j) * DOUT + c];
        unsigned hb = f2bf_bits(w);
        unsigned lb = f2bf_bits(w - bf_lo(hb));
        h8[j] = (short)hb; l8[j] = (short)lb;
    }
    *reinterpret_cast<short8*>(&Wh[(size_t)idx * 8]) = h8;
    *reinterpret_cast<short8*>(&Wl[(size_t)idx * 8]) = l8;
}

__global__ __launch_bounds__(256) void prepack_all_kernel(const float* __restrict__ W1,
                                                          const float* __restrict__ W2,
                                                          const float* __restrict__ W3,
                                                          short* __restrict__ w1h, short* __restrict__ w1l,
                                                          short* __restrict__ w2h, short* __restrict__ w2l,
                                                          short* __restrict__ w3h, short* __restrict__ w3l,
                                                          int* __restrict__ bkt_cursor) {
    int idx = blockIdx.x * 256 + threadIdx.x;
    if (idx < 2048)      prepack_one(W1, w1h, w1l, 128, idx);
    else if (idx < 3072) prepack_one(W2, w2h, w2l, 64,  idx - 2048);
    else if (idx < 3328) prepack_one(W3, w3h, w3l, 32,  idx - 3072);
    else if (idx < 3584) bkt_cursor[idx - 3328] = 0;
}

// ---------------- merged: edge binning (blocks < NBE)  ∥  layer-1 GEMM (blocks >= NBE) ------------

struct BinSh {
    int qcnt[256];
    int qofs[256];
    int gbase[256];
    uint2 staging[4096];
};
struct GemmSh {
    unsigned Xh[64 * 64];
    unsigned Xl[64 * 64];
};
union SharedU { BinSh b; GemmSh g; };

__global__ __launch_bounds__(512) void bin_gemm1_kernel(const int* __restrict__ src,
                                                        const int* __restrict__ dst, int E,
                                                        int* __restrict__ bkt_cursor,
                                                        unsigned* __restrict__ bin,
                                                        const float* __restrict__ X,
                                                        const short8* __restrict__ Wp_hi,
                                                        const short8* __restrict__ Wp_lo,
                                                        unsigned* __restrict__ G,
                                                        int n, int NBE) {
    __shared__ SharedU sh;
    const int t = threadIdx.x;

    if ((int)blockIdx.x < NBE) {
        const int e0 = (int)blockIdx.x * 4096;
        if (t < 256) sh.b.qcnt[t] = 0;
        __syncthreads();
        int sa[8], da[8], slot[8];
#pragma unroll
        for (int k = 0; k < 8; ++k) {
            int e = e0 + k * 512 + t;
            sa[k] = -1; da[k] = 0; slot[k] = 0;
            if (e < E) {
                int ss = src[e], dd = dst[e];
                if (ss >= 0 && ss < n && dd >= 0 && dd < n) {
                    sa[k] = ss; da[k] = dd;
                    slot[k] = atomicAdd(&sh.b.qcnt[dd >> 8], 1);
                }
            }
        }
        __syncthreads();
        if (t < 256) sh.b.qofs[t] = sh.b.qcnt[t];
        __syncthreads();
        for (int off = 1; off < 256; off <<= 1) {
            int val = 0;
            if (t < 256 && t >= off) val = sh.b.qofs[t - off];
            __syncthreads();
            if (t < 256) sh.b.qofs[t] += val;
            __syncthreads();
        }
        if (t < 256) {
            int myc = sh.b.qcnt[t];
            if (myc > 0) sh.b.gbase[t] = atomicAdd(&bkt_cursor[t], myc);
            sh.b.qofs[t] -= myc;
        }
        __syncthreads();
#pragma unroll
        for (int k = 0; k < 8; ++k) {
            if (sa[k] >= 0)
                sh.b.staging[sh.b.qofs[da[k] >> 8] + slot[k]] =
                    make_uint2((unsigned)sa[k], (unsigned)da[k]);
        }
        __syncthreads();
        const int tot = sh.b.qofs[255] + sh.b.qcnt[255];
        for (int i = t; i < tot; i += 512) {
            uint2 en = sh.b.staging[i];
            int b = (int)(en.y >> 8);
            int pos = sh.b.gbase[b] + (i - sh.b.qofs[b]);
            if (pos < CAP)
                bin[(size_t)b * CAP + pos] = ((en.y & 255u) << 24) | en.x;
        }
        return;
    }

    // ---- layer-1 GEMM body: DIN=128, DOUT=128, UNSCALED output ----
    constexpr int NT = 8, NTW = 4, NK = 4, WPR = 64;
    const int row0 = ((int)blockIdx.x - NBE) * 64;

    for (int i = t * 4; i < 64 * 128; i += 2048) {
        int r = i / 128, c = i % 128;
        float4 v = make_float4(0.f, 0.f, 0.f, 0.f);
        if (row0 + r < n) v = *reinterpret_cast<const float4*>(&X[(size_t)(row0 + r) * 128 + c]);
        unsigned h0 = f2bf_bits(v.x), h1 = f2bf_bits(v.y), h2 = f2bf_bits(v.z), h3 = f2bf_bits(v.w);
        unsigned l0 = f2bf_bits(v.x - bf_lo(h0)), l1 = f2bf_bits(v.y - bf_lo(h1));
        unsigned l2 = f2bf_bits(v.z - bf_lo(h2)), l3 = f2bf_bits(v.w - bf_lo(h3));
        int w = (r * WPR + c / 2) ^ ((r & 7) << 2);
        *reinterpret_cast<uint2*>(&sh.g.Xh[w]) = make_uint2(h0 | (h1 << 16), h2 | (h3 << 16));
        *reinterpret_cast<uint2*>(&sh.g.Xl[w]) = make_uint2(l0 | (l1 << 16), l2 | (l3 << 16));
    }
    __syncthreads();

    const int lane = t & 63, wid = t >> 6;
    const int strip = wid >> 1, half = wid & 1;
    const int g = lane >> 4, cl = lane & 15;
    const int lrow = strip * 16 + cl;
    f32x4 acc[NTW];
#pragma unroll
    for (int i = 0; i < NTW; ++i) acc[i] = (f32x4){0.f, 0.f, 0.f, 0.f};

#pragma unroll
    for (int kk = 0; kk < NK; ++kk) {
        int wb = (lrow * WPR + kk * 16 + g * 4) ^ ((lrow & 7) << 2);
        short8 xh = *reinterpret_cast<const short8*>(&sh.g.Xh[wb]);
        short8 xl = *reinterpret_cast<const short8*>(&sh.g.Xl[wb]);
#pragma unroll
        for (int i = 0; i < NTW; ++i) {
            int ct = half * NTW + i;
            short8 wh = Wp_hi[(kk * NT + ct) * 64 + lane];
            short8 wl = Wp_lo[(kk * NT + ct) * 64 + lane];
            acc[i] = __builtin_amdgcn_mfma_f32_16x16x32_bf16(wh, xh, acc[i], 0, 0, 0);
            acc[i] = __builtin_amdgcn_mfma_f32_16x16x32_bf16(wh, xl, acc[i], 0, 0, 0);
            acc[i] = __builtin_amdgcn_mfma_f32_16x16x32_bf16(wl, xh, acc[i], 0, 0, 0);
        }
    }

    const int r = row0 + lrow;
    if (r < n) {
#pragma unroll
        for (int i = 0; i < NTW; ++i) {
            int c0 = (half * NTW + i) * 16 + g * 4;
            unsigned p0 = f2bf_bits(acc[i][0]) | (f2bf_bits(acc[i][1]) << 16);
            unsigned p1 = f2bf_bits(acc[i][2]) | (f2bf_bits(acc[i][3]) << 16);
            *reinterpret_cast<uint2*>(&G[(size_t)r * 64 + c0 / 2]) = make_uint2(p0, p1);
        }
    }
}

// per-bucket: counting sort by (dst_local, src>>13) -> csr per-node lists SORTED BY SRC SLICE
// (slice = 8192 nodes = 2 MB of g1 -> fits every XCD's 4 MB L2; all blocks sweep slices in
// rough lockstep -> gathers become L2-local). Also: off2, dinv, g1 pre-scale.
__global__ __launch_bounds__(256) void bucket_offsets_fill_kernel(const unsigned* __restrict__ bin,
                                                                  const int* __restrict__ bkt_cursor,
                                                                  int2* __restrict__ off2,
                                                                  float* __restrict__ dinv,
                                                                  int* __restrict__ csr,
                                                                  unsigned* __restrict__ g1, int n) {
    constexpr int NSL = 8;              // src slices (src>>13, max 6 for N=50000)
    __shared__ int cnt2[256 * NSL];     // (dst_local, slice) counts -> cursors
    __shared__ int part[256];
    __shared__ float sdinv[256];
    const int t = threadIdx.x;
    const int b = blockIdx.x;
    const int S = b * CAP;
    const int count = min(bkt_cursor[b], CAP);

    for (int i = t; i < 256 * NSL; i += 256) cnt2[i] = 0;
    __syncthreads();
    for (int i = t; i < count; i += 256) {
        unsigned p = bin[S + i];
        int key = (int)((p >> 24) << 3) | (int)((p & 0xFFFFFFu) >> 13);
        atomicAdd(&cnt2[key], 1);
    }
    __syncthreads();
    // blocked exclusive scan over 2048 cells: thread t owns cells [t*8, t*8+8)
    const int base = t * NSL;
    int loc[NSL];
    int s0 = 0;
#pragma unroll
    for (int k = 0; k < NSL; ++k) { loc[k] = s0; s0 += cnt2[base + k]; }
    part[t] = s0;
    __syncthreads();
    for (int off = 1; off < 256; off <<= 1) {
        int val = (t >= off) ? part[t - off] : 0;
        __syncthreads();
        part[t] += val;
        __syncthreads();
    }
    const int nbase = S + ((t == 0) ? 0 : part[t - 1]);   // node-exclusive base
    const int c = s0;                                      // node degree
#pragma unroll
    for (int k = 0; k < NSL; ++k) cnt2[base + k] = nbase + loc[k];   // global cursors
    const float dv = rsqrtf((float)(c + 1));
    sdinv[t] = dv;
    const int node0 = b * 256;
    const int node = node0 + t;
    if (node < n) {
        off2[node] = make_int2(nbase, nbase + c);
        dinv[node] = dv;
    }
    __syncthreads();
    // fill csr in (node, slice)-sorted order
    for (int i = t; i < count; i += 256) {
        unsigned p = bin[S + i];
        int key = (int)((p >> 24) << 3) | (int)((p & 0xFFFFFFu) >> 13);
        int pos = atomicAdd(&cnt2[key], 1);
        csr[pos] = (int)(p & 0xFFFFFFu);
    }
    // pre-scale g1 rows of this bucket: g1[v] *= dinv[v]
    const int rows = min(256, n - node0);
    uint4* g4 = reinterpret_cast<uint4*>(g1 + (size_t)node0 * 64);
    for (int i = t; i < rows * 16; i += 256) {
        const float s = sdinv[i >> 4];
        uint4 v = g4[i];
        unsigned r0 = f2bf_bits(s * bf_lo(v.x)) | (f2bf_bits(s * bf_hi(v.x)) << 16);
        unsigned r1 = f2bf_bits(s * bf_lo(v.y)) | (f2bf_bits(s * bf_hi(v.y)) << 16);
        unsigned r2 = f2bf_bits(s * bf_lo(v.z)) | (f2bf_bits(s * bf_hi(v.z)) << 16);
        unsigned r3 = f2bf_bits(s * bf_lo(v.w)) | (f2bf_bits(s * bf_hi(v.w)) << 16);
        g4[i] = make_uint4(r0, r1, r2, r3);
    }
}

// ------- FUSED: h[v] = relu(dinv[v]*(g[v]+Σ g[u]) + b)  ->  Gout = bf16(diag(dinv)·(h @ W)) -------

template<int DIN, int DOUT>
__global__ __launch_bounds__(512, 4) void fused_agg_gemm_kernel(const unsigned* __restrict__ Gin,
                                                                const int2* __restrict__ off2,
                                                                const int* __restrict__ csr,
                                                                const float* __restrict__ dinv,
                                                                const float* __restrict__ bias,
                                                                const short8* __restrict__ Wp_hi,
                                                                const short8* __restrict__ Wp_lo,
                                                                unsigned* __restrict__ Gout, int n) {
    constexpr int NT    = DOUT / 16;
    constexpr int NTW   = NT / 2;
    constexpr int NK    = DIN / 32;
    constexpr int WPR   = DIN / 2;
    constexpr int W4    = DIN / 8;
    constexpr int LPN   = W4;
    constexpr int SLOTS = 512 / LPN;
    constexpr int ROUNDS = 64 / SLOTS;
    constexpr int STG   = 2048;
    __shared__ unsigned Xh[64 * WPR];
    __shared__ unsigned Xl[64 * WPR];
    __shared__ int scsr[STG];
    const int t = threadIdx.x;
    const int node0 = blockIdx.x * 64;
    const int slot = t / LPN, cw = t % LPN;
    const uint4* gB = reinterpret_cast<const uint4*>(Gin) + cw;
    const int col = cw * 8;
    const float4 bs0 = *reinterpret_cast<const float4*>(&bias[col]);
    const float4 bs1 = *reinterpret_cast<const float4*>(&bias[col + 4]);

    const int blkS = off2[node0].x;
    const int blkE = off2[min(node0 + 63, n - 1)].y;
    const int stg = min(blkE - blkS, STG);
    for (int i = t; i < stg; i += 512) scsr[i] = csr[blkS + i];
    __syncthreads();

#pragma unroll
    for (int rd = 0; rd < ROUNDS; ++rd) {
        const int r = rd * SLOTS + slot;
        const int v = node0 + r;
        unsigned hw[4] = {0u, 0u, 0u, 0u}, lw[4] = {0u, 0u, 0u, 0u};
        if (v < n) {
            float a[8], b[8];
            uint4 us = gB[(size_t)v * W4];
            a[0] = bf_lo(us.x); a[1] = bf_hi(us.x); a[2] = bf_lo(us.y); a[3] = bf_hi(us.y);
            a[4] = bf_lo(us.z); a[5] = bf_hi(us.z); a[6] = bf_lo(us.w); a[7] = bf_hi(us.w);
#pragma unroll
            for (int q = 0; q < 8; ++q) b[q] = 0.f;
            const int2 se = off2[v];
            int j = se.x;
            for (; j + 8 <= se.y; j += 8) {
                int k = j - blkS;
                int u0, u1, u2, u3, u4, u5, u6, u7;
                if (k + 8 <= stg) {
                    u0 = scsr[k];     u1 = scsr[k + 1]; u2 = scsr[k + 2]; u3 = scsr[k + 3];
                    u4 = scsr[k + 4]; u5 = scsr[k + 5]; u6 = scsr[k + 6]; u7 = scsr[k + 7];
                } else {
                    u0 = csr[j];      u1 = csr[j + 1];  u2 = csr[j + 2];  u3 = csr[j + 3];
                    u4 = csr[j + 4];  u5 = csr[j + 5];  u6 = csr[j + 6];  u7 = csr[j + 7];
                }
                uint4 x0 = gB[(size_t)u0 * W4];
                uint4 x1 = gB[(size_t)u1 * W4];
                uint4 x2 = gB[(size_t)u2 * W4];
                uint4 x3 = gB[(size_t)u3 * W4];
                uint4 x4 = gB[(size_t)u4 * W4];
                uint4 x5 = gB[(size_t)u5 * W4];
                uint4 x6 = gB[(size_t)u6 * W4];
                uint4 x7 = gB[(size_t)u7 * W4];
                a[0] += bf_lo(x0.x); a[1] += bf_hi(x0.x); a[2] += bf_lo(x0.y); a[3] += bf_hi(x0.y);
                a[4] += bf_lo(x0.z); a[5] += bf_hi(x0.z); a[6] += bf_lo(x0.w); a[7] += bf_hi(x0.w);
                b[0] += bf_lo(x1.x); b[1] += bf_hi(x1.x); b[2] += bf_lo(x1.y); b[3] += bf_hi(x1.y);
                b[4] += bf_lo(x1.z); b[5] += bf_hi(x1.z); b[6] += bf_lo(x1.w); b[7] += bf_hi(x1.w);
                a[0] += bf_lo(x2.x); a[1] += bf_hi(x2.x); a[2] += bf_lo(x2.y); a[3] += bf_hi(x2.y);
                a[4] += bf_lo(x2.z); a[5] += bf_hi(x2.z); a[6] += bf_lo(x2.w); a[7] += bf_hi(x2.w);
                b[0] += bf_lo(x3.x); b[1] += bf_hi(x3.x); b[2] += bf_lo(x3.y); b[3] += bf_hi(x3.y);
                b[4] += bf_lo(x3.z); b[5] += bf_hi(x3.z); b[6] += bf_lo(x3.w); b[7] += bf_hi(x3.w);
                a[0] += bf_lo(x4.x); a[1] += bf_hi(x4.x); a[2] += bf_lo(x4.y); a[3] += bf_hi(x4.y);
                a[4] += bf_lo(x4.z); a[5] += bf_hi(x4.z); a[6] += bf_lo(x4.w); a[7] += bf_hi(x4.w);
                b[0] += bf_lo(x5.x); b[1] += bf_hi(x5.x); b[2] += bf_lo(x5.y); b[3] += bf_hi(x5.y);
                b[4] += bf_lo(x5.z); b[5] += bf_hi(x5.z); b[6] += bf_lo(x5.w); b[7] += bf_hi(x5.w);
                a[0] += bf_lo(x6.x); a[1] += bf_hi(x6.x); a[2] += bf_lo(x6.y); a[3] += bf_hi(x6.y);
                a[4] += bf_lo(x6.z); a[5] += bf_hi(x6.z); a[6] += bf_lo(x6.w); a[7] += bf_hi(x6.w);
                b[0] += bf_lo(x7.x); b[1] += bf_hi(x7.x); b[2] += bf_lo(x7.y); b[3] += bf_hi(x7.y);
                b[4] += bf_lo(x7.z); b[5] += bf_hi(x7.z); b[6] += bf_lo(x7.w); b[7] += bf_hi(x7.w);
            }
            for (; j < se.y; ++j) {
                int k = j - blkS;
                int u0 = (k < stg) ? scsr[k] : csr[j];
                uint4 x0 = gB[(size_t)u0 * W4];
                a[0] += bf_lo(x0.x); a[1] += bf_hi(x0.x); a[2] += bf_lo(x0.y); a[3] += bf_hi(x0.y);
                a[4] += bf_lo(x0.z); a[5] += bf_hi(x0.z); a[6] += bf_lo(x0.w); a[7] += bf_hi(x0.w);
            }
            const float dv = dinv[v];
            const float bb[8] = {bs0.x, bs0.y, bs0.z, bs0.w, bs1.x, bs1.y, bs1.z, bs1.w};
#pragma unroll
            for (int q = 0; q < 8; ++q) {
                float o = fmaxf(dv * (a[q] + b[q]) + bb[q], 0.f);   // ReLU
                unsigned hb = f2bf_bits(o);
                unsigned lb = f2bf_bits(o - bf_lo(hb));
                hw[q >> 1] |= (q & 1) ? (hb << 16) : hb;
                lw[q >> 1] |= (q & 1) ? (lb << 16) : lb;
            }
        }
        const int w0 = (r * WPR + cw * 4) ^ ((r & 7) << 2);
        *reinterpret_cast<uint4*>(&Xh[w0]) = make_uint4(hw[0], hw[1], hw[2], hw[3]);
        *reinterpret_cast<uint4*>(&Xl[w0]) = make_uint4(lw[0], lw[1], lw[2], lw[3]);
    }
    __syncthreads();

    const int lane = t & 63, wid = t >> 6;
    const int strip = wid >> 1, half = wid & 1;
    const int g = lane >> 4, cl = lane & 15;
    const int lrow = strip * 16 + cl;
    f32x4 acc[NTW];
#pragma unroll
    for (int i = 0; i < NTW; ++i) acc[i] = (f32x4){0.f, 0.f, 0.f, 0.f};

#pragma unroll
    for (int kk = 0; kk < NK; ++kk) {
        int wb = (lrow * WPR + kk * 16 + g * 4) ^ ((lrow & 7) << 2);
        short8 xh = *reinterpret_cast<const short8*>(&Xh[wb]);
        short8 xl = *reinterpret_cast<const short8*>(&Xl[wb]);
#pragma unroll
        for (int i = 0; i < NTW; ++i) {
            int ct = half * NTW + i;
            short8 wh = Wp_hi[(kk * NT + ct) * 64 + lane];
            short8 wl = Wp_lo[(kk * NT + ct) * 64 + lane];
            acc[i] = __builtin_amdgcn_mfma_f32_16x16x32_bf16(wh, xh, acc[i], 0, 0, 0);
            acc[i] = __builtin_amdgcn_mfma_f32_16x16x32_bf16(wh, xl, acc[i], 0, 0, 0);
            acc[i] = __builtin_amdgcn_mfma_f32_16x16x32_bf16(wl, xh, acc[i], 0, 0, 0);
        }
    }

    const int r = node0 + lrow;
    if (r < n) {
        const float s = dinv[r];
#pragma unroll
        for (int i = 0; i < NTW; ++i) {
            int c0 = (half * NTW + i) * 16 + g * 4;
            unsigned p0 = f2bf_bits(acc[i][0] * s) | (f2bf_bits(acc[i][1] * s) << 16);
            unsigned p1 = f2bf_bits(acc[i][2] * s) | (f2bf_bits(acc[i][3] * s) << 16);
            *reinterpret_cast<uint2*>(&Gout[(size_t)r * (DOUT / 2) + c0 / 2]) = make_uint2(p0, p1);
        }
    }
}

// -------- Final aggregate (D=32, no relu, fp32 out) --------

__global__ __launch_bounds__(256, 4) void aggregate_final_kernel(const unsigned* __restrict__ G,
                                                                 const int2* __restrict__ off2,
                                                                 const int* __restrict__ csr,
                                                                 const float* __restrict__ dinv,
                                                                 const float* __restrict__ bias,
                                                                 float* __restrict__ out, int n) {
    constexpr int D = 32, W2u = 8, LPN = 8, STG = 1024;
    __shared__ int scsr[STG];
    const int t = threadIdx.x;
    const int v0 = blockIdx.x * 32;
    const int blkS = off2[v0].x;
    const int blkE = off2[min(v0 + 31, n - 1)].y;
    const int stg = min(blkE - blkS, STG);
    for (int i = t; i < stg; i += 256) scsr[i] = csr[blkS + i];
    __syncthreads();

    const int v = v0 + t / LPN;
    if (v >= n) return;
    const int cw = t % LPN;
    const uint2* gB = reinterpret_cast<const uint2*>(G) + cw;

    float a[4], b[4];
    uint2 us = gB[(size_t)v * W2u];
    a[0] = bf_lo(us.x); a[1] = bf_hi(us.x); a[2] = bf_lo(us.y); a[3] = bf_hi(us.y);
#pragma unroll
    for (int q = 0; q < 4; ++q) b[q] = 0.f;

    const int2 se = off2[v];
    int j = se.x;
    for (; j + 8 <= se.y; j += 8) {
        int k = j - blkS;
        int u0, u1, u2, u3, u4, u5, u6, u7;
        if (k + 8 <= stg) {
            u0 = scsr[k];     u1 = scsr[k + 1]; u2 = scsr[k + 2]; u3 = scsr[k + 3];
            u4 = scsr[k + 4]; u5 = scsr[k + 5]; u6 = scsr[k + 6]; u7 = scsr[k + 7];
        } else {
            u0 = csr[j];      u1 = csr[j + 1];  u2 = csr[j + 2];  u3 = csr[j + 3];
            u4 = csr[j + 4];  u5 = csr[j + 5];  u6 = csr[j + 6];  u7 = csr[j + 7];
        }
        uint2 x0 = gB[(size_t)u0 * W2u];
        uint2 x1 = gB[(size_t)u1 * W2u];
        uint2 x2 = gB[(size_t)u2 * W2u];
        uint2 x3 = gB[(size_t)u3 * W2u];
        uint2 x4 = gB[(size_t)u4 * W2u];
        uint2 x5 = gB[(size_t)u5 * W2u];
        uint2 x6 = gB[(size_t)u6 * W2u];
        uint2 x7 = gB[(size_t)u7 * W2u];
        a[0] += bf_lo(x0.x); a[1] += bf_hi(x0.x); a[2] += bf_lo(x0.y); a[3] += bf_hi(x0.y);
        b[0] += bf_lo(x1.x); b[1] += bf_hi(x1.x); b[2] += bf_lo(x1.y); b[3] += bf_hi(x1.y);
        a[0] += bf_lo(x2.x); a[1] += bf_hi(x2.x); a[2] += bf_lo(x2.y); a[3] += bf_hi(x2.y);
        b[0] += bf_lo(x3.x); b[1] += bf_hi(x3.x); b[2] += bf_lo(x3.y); b[3] += bf_hi(x3.y);
        a[0] += bf_lo(x4.x); a[1] += bf_hi(x4.x); a[2] += bf_lo(x4.y); a[3] += bf_hi(x4.y);
        b[0] += bf_lo(x5.x); b[1] += bf_hi(x5.x); b[2] += bf_lo(x5.y); b[3] += bf_hi(x5.y);
        a[0] += bf_lo(x6.x); a[1] += bf_hi(x6.x); a[2] += bf_lo(x6.y); a[3] += bf_hi(x6.y);
        b[0] += bf_lo(x7.x); b[1] += bf_hi(x7.x); b[2] += bf_lo(x7.y); b[3] += bf_hi(x7.y);
    }
    for (; j < se.y; ++j) {
        int k = j - blkS;
        int u0 = (k < stg) ? scsr[k] : csr[j];
        uint2 x0 = gB[(size_t)u0 * W2u];
        a[0] += bf_lo(x0.x); a[1] += bf_hi(x0.x); a[2] += bf_lo(x0.y); a[3] += bf_hi(x0.y);
    }

    const float dv = dinv[v];
    const int col = cw * 4;
    const float4 bs = *reinterpret_cast<const float4*>(&bias[col]);
    float4 o = make_float4(dv * (a[0] + b[0]) + bs.x, dv * (a[1] + b[1]) + bs.y,
                           dv * (a[2] + b[2]) + bs.z, dv * (a[3] + b[3]) + bs.w);
    *reinterpret_cast<float4*>(&out[(size_t)v * D + col]) = o;
}

// ---------------- launch ----------------

extern "C" void kernel_launch(void* const* d_in, const int* in_sizes, int n_in,
                              void* d_out, int out_size, void* d_ws, size_t ws_size,
                              hipStream_t stream) {
    const int N = 50000, E = 800000;
    const int NB  = (N + 255) / 256;
    const int NBE = (E + 4095) / 4096;
    const int NG  = (N + 63) / 64;
    const float* x  = (const float*)d_in[0];
    const int* ei = (const int*)d_in[1];
    const int* src = ei;
    const int* dst = ei + E;
    const float* W1 = (const float*)d_in[2]; const float* b1 = (const float*)d_in[3];
    const float* W2 = (const float*)d_in[4]; const float* b2 = (const float*)d_in[5];
    const float* W3 = (const float*)d_in[6]; const float* b3 = (const float*)d_in[7];
    float* out = (float*)d_out;

    char* ws = (char*)d_ws;
    size_t off = 0;
    auto alloc = [&](size_t bytes) -> void* {
        void* p = ws + off;
        off = (off + bytes + 255) & ~(size_t)255;
        return p;
    };
    int2*     off2       = (int2*)alloc((size_t)N * 8);
    float*    dinv       = (float*)alloc((size_t)N * 4);
    int*      csr        = (int*)alloc((size_t)NB * CAP * 4);
    unsigned* bin        = (unsigned*)alloc((size_t)NB * CAP * 4);
    unsigned* g1         = (unsigned*)alloc((size_t)N * 64 * 4);
    unsigned* g2         = (unsigned*)alloc((size_t)N * 32 * 4);
    unsigned* g3         = (unsigned*)alloc((size_t)N * 16 * 4);
    int*      bkt_cursor = (int*)alloc((size_t)256 * 4);
    short*    wp1h = (short*)alloc((size_t)128 * 128 * 2);
    short*    wp1l = (short*)alloc((size_t)128 * 128 * 2);
    short*    wp2h = (short*)alloc((size_t)128 * 64 * 2);
    short*    wp2l = (short*)alloc((size_t)128 * 64 * 2);
    short*    wp3h = (short*)alloc((size_t)64 * 32 * 2);
    short*    wp3l = (short*)alloc((size_t)64 * 32 * 2);
    (void)ws_size; (void)n_in; (void)in_sizes; (void)out_size;

    prepack_all_kernel<<<14, 256, 0, stream>>>(W1, W2, W3, wp1h, wp1l, wp2h, wp2l, wp3h, wp3l,
                                               bkt_cursor);
    bin_gemm1_kernel<<<NBE + NG, 512, 0, stream>>>(src, dst, E, bkt_cursor, bin,
                                                   x, (const short8*)wp1h, (const short8*)wp1l,
                                                   g1, N, NBE);
    bucket_offsets_fill_kernel<<<NB, 256, 0, stream>>>(bin, bkt_cursor, off2, dinv, csr, g1, N);
    fused_agg_gemm_kernel<128, 64><<<NG, 512, 0, stream>>>(g1, off2, csr, dinv, b1,
                                                           (const short8*)wp2h,
                                                           (const short8*)wp2l, g2, N);
    fused_agg_gemm_kernel<64, 32><<<NG, 512, 0, stream>>>(g2, off2, csr, dinv, b2,
                                                          (const short8*)wp3h,
                                                          (const short8*)wp3l, g3, N);
    aggregate_final_kernel<<<(N * 8 + 255) / 256, 256, 0, stream>>>(g3, off2, csr, dinv, b3, out, N);
}